// Round 1
// baseline (1132.169 us; speedup 1.0000x reference)
//
#include <hip/hip_runtime.h>
#include <hip/hip_bf16.h>
#include <math.h>

// MoELanguageZone: embed -> sigmoid(enc) -> s2c -> router(top2 of 8) ->
// 8 experts (relu mlp) weighted combine -> sigmoid(c2s) -> sigmoid(dec) -> out logits
// N=4096 tokens, D=H=1024, M=64, E=8, HE=512, V=32000.
// bf16 MFMA (16x16x32) for all big GEMMs; fp32 for s2c/router (top-k stability).
// All MFMA operands use k-packed layout pk[kb][row][j] (k = kb*8+j) so staging is
// global_load_lds width-16 friendly and fragments are single ds_read_b128.

typedef __bf16 bf16x8 __attribute__((ext_vector_type(8)));
typedef float f32x4 __attribute__((ext_vector_type(4)));

__device__ __forceinline__ ushort f2bf(float f) {
  union { float f; unsigned u; } v; v.f = f;
  unsigned u = v.u;
  u += 0x7FFFu + ((u >> 16) & 1u);   // RNE
  return (ushort)(u >> 16);
}

__device__ __forceinline__ void async16(const void* g, void* l) {
  __builtin_amdgcn_global_load_lds((const __attribute__((address_space(1))) void*)g,
                                   (__attribute__((address_space(3))) void*)l,
                                   16, 0, 0);
}

// ---------------- pack fp32 row-major (K x N) -> bf16 pk [K/8][N][8] ----------------
__global__ void pack_w_kernel(const float* __restrict__ W, ushort* __restrict__ Wpk,
                              int K, int N) {
  long t = (long)blockIdx.x * blockDim.x + threadIdx.x;
  long total = (long)(K >> 3) * N;
  if (t >= total) return;
  long kb = t / N;
  int n = (int)(t - kb * N);
  long zoff = (long)blockIdx.y * K * N;
  const float* src = W + zoff + (kb * 8) * (long)N + n;
  union { ushort u[8]; uint4 v; } o;
#pragma unroll
  for (int j = 0; j < 8; ++j) o.u[j] = f2bf(src[(long)j * N]);
  *(uint4*)(Wpk + zoff + t * 8) = o.v;
}

// ---------------- embedding gather -> x pk [128][M][8] ----------------
__global__ void embed_pk_kernel(const int* __restrict__ ids, const float* __restrict__ emb,
                                ushort* __restrict__ xpk, int M) {
  int m = blockIdx.x * blockDim.x + threadIdx.x;  // token
  int kb = blockIdx.y;                            // 0..127
  long id = ids[m];
  const float4* s = (const float4*)(emb + id * 1024 + kb * 8);
  float4 a = s[0], b = s[1];
  union { ushort u[8]; uint4 v; } o;
  o.u[0] = f2bf(a.x); o.u[1] = f2bf(a.y); o.u[2] = f2bf(a.z); o.u[3] = f2bf(a.w);
  o.u[4] = f2bf(b.x); o.u[5] = f2bf(b.y); o.u[6] = f2bf(b.z); o.u[7] = f2bf(b.w);
  *(uint4*)(xpk + ((size_t)kb * M + m) * 8) = o.v;
}

// ---------------- generic pk-bf16 MFMA GEMM ----------------
// A: pk [K/8][M][8], B: pk [K/8][N][8], C: fp32 row-major (OUT=0) or pk bf16 (OUT=1)
// ACT: 0 none, 1 sigmoid, 2 relu.  batched via blockIdx.z with element strides.
template <int WAVES_M, int WAVES_N, int WM, int WN, int ACT, int OUT>
__launch_bounds__(WAVES_M * WAVES_N * 64)
__global__ void gemm_pk(const ushort* __restrict__ A, const ushort* __restrict__ B,
                        const float* __restrict__ bias, void* __restrict__ Cout,
                        int M, int N, int K, long sA, long sB, long sBias, long sC) {
  constexpr int BM = WAVES_M * WM * 16;
  constexpr int BN = WAVES_N * WN * 16;
  constexpr int NW = WAVES_M * WAVES_N;
  constexpr int ACH = 8 * BM / 64;  // 16B-chunk wave-instructions per A k-tile
  constexpr int BCH = 8 * BN / 64;

  __shared__ ushort As[8 * BM * 8];
  __shared__ ushort Bs[8 * BN * 8];

  const int tid = threadIdx.x;
  const int lane = tid & 63;
  const int wave = tid >> 6;
  const int wm = wave % WAVES_M;
  const int wn = wave / WAVES_M;
  const int m0 = blockIdx.x * BM;
  const int n0 = blockIdx.y * BN;
  const int z = blockIdx.z;

  A += (size_t)z * sA;
  B += (size_t)z * sB;
  const float* biasp = bias + (size_t)z * sBias;

  f32x4 acc[WM][WN] = {};

  const int ktiles = K >> 6;
  const int q = lane >> 4;
  const int r16 = lane & 15;

  for (int kt = 0; kt < ktiles; ++kt) {
    const int kb0 = kt * 8;
    // ---- stage A tile (BK=64) via global_load_lds, 16B/lane ----
#pragma unroll
    for (int c = wave; c < ACH; c += NW) {
      int kb = c / (BM / 64);
      int hh = c % (BM / 64);
      const ushort* g = A + (((size_t)(kb0 + kb)) * M + m0 + hh * 64 + lane) * 8;
      ushort* l = &As[(kb * BM + hh * 64) * 8];
      async16(g, l);
    }
#pragma unroll
    for (int c = wave; c < BCH; c += NW) {
      int kb = c / (BN / 64);
      int hh = c % (BN / 64);
      const ushort* g = B + (((size_t)(kb0 + kb)) * N + n0 + hh * 64 + lane) * 8;
      ushort* l = &Bs[(kb * BN + hh * 64) * 8];
      async16(g, l);
    }
    __syncthreads();
    // ---- compute: 2 k-halves of 32 ----
#pragma unroll
    for (int kk = 0; kk < 2; ++kk) {
      bf16x8 a[WM], b[WN];
#pragma unroll
      for (int mt = 0; mt < WM; ++mt)
        a[mt] = *(const bf16x8*)&As[((kk * 4 + q) * BM + wm * WM * 16 + mt * 16 + r16) * 8];
#pragma unroll
      for (int nt = 0; nt < WN; ++nt)
        b[nt] = *(const bf16x8*)&Bs[((kk * 4 + q) * BN + wn * WN * 16 + nt * 16 + r16) * 8];
#pragma unroll
      for (int mt = 0; mt < WM; ++mt)
#pragma unroll
        for (int nt = 0; nt < WN; ++nt)
          acc[mt][nt] = __builtin_amdgcn_mfma_f32_16x16x32_bf16(a[mt], b[nt], acc[mt][nt], 0, 0, 0);
    }
    __syncthreads();
  }

  // ---- epilogue: bias + activation + store ----
#pragma unroll
  for (int mt = 0; mt < WM; ++mt) {
#pragma unroll
    for (int nt = 0; nt < WN; ++nt) {
      int col = n0 + wn * WN * 16 + nt * 16 + r16;
      float bv = biasp[col];
#pragma unroll
      for (int r = 0; r < 4; ++r) {
        int row = m0 + wm * WM * 16 + mt * 16 + q * 4 + r;
        float v = acc[mt][nt][r] + bv;
        if (ACT == 1) v = 1.f / (1.f + expf(-v));
        else if (ACT == 2) v = fmaxf(v, 0.f);
        if (OUT == 0) {
          ((float*)Cout)[(size_t)z * sC + (size_t)row * N + col] = v;
        } else {
          ((ushort*)Cout)[(size_t)z * sC + ((size_t)(col >> 3) * M + row) * 8 + (col & 7)] = f2bf(v);
        }
      }
    }
  }
}

// ---------------- fp32 s2c: cont = spikes(Mx1024) @ W(1024x64) + b ----------------
__global__ void s2c_kernel(const float* __restrict__ spikes, const float* __restrict__ W,
                           const float* __restrict__ b, float* __restrict__ cont,
                           ushort* __restrict__ contpk, int M) {
  int tid = threadIdx.x;
  int m = tid & 63;
  int n = blockIdx.x * 4 + (tid >> 6);
  const float* srow = spikes + (size_t)n * 1024;
  float acc = b[m];
#pragma unroll 8
  for (int k = 0; k < 1024; ++k) acc = fmaf(srow[k], W[k * 64 + m], acc);
  cont[(size_t)n * 64 + m] = acc;
  contpk[((size_t)(m >> 3) * M + n) * 8 + (m & 7)] = f2bf(acc);
}

// ---------------- router: tanh MLP -> softmax(8) -> top2 renorm ----------------
__global__ void router_kernel(const float* __restrict__ cont, const float* __restrict__ rW1,
                              const float* __restrict__ rb1, const float* __restrict__ rW2,
                              const float* __restrict__ rb2, float* __restrict__ probs,
                              float* __restrict__ wfull) {
  int n = blockIdx.x;
  int L = threadIdx.x;  // 64
  float c = cont[(size_t)n * 64 + L];
  float gh = rb1[L];
#pragma unroll 8
  for (int k = 0; k < 64; ++k) {
    float ck = __shfl(c, k, 64);
    gh = fmaf(ck, rW1[k * 64 + L], gh);
  }
  gh = tanhf(gh);
  __shared__ float ghs[64];
  ghs[L] = gh;
  __syncthreads();
  float lg = 0.f;
  if (L < 8) {
    lg = rb2[L];
#pragma unroll 8
    for (int h = 0; h < 64; ++h) lg = fmaf(ghs[h], rW2[h * 8 + L], lg);
  }
  float mx = lg;
  for (int o = 4; o >= 1; o >>= 1) mx = fmaxf(mx, __shfl_xor(mx, o, 8));
  float ex = expf(lg - mx);
  float sm = ex;
  for (int o = 4; o >= 1; o >>= 1) sm += __shfl_xor(sm, o, 8);
  float pr = ex / sm;
  __shared__ float ps[8];
  if (L < 8) { probs[(size_t)n * 8 + L] = pr; ps[L] = pr; }
  __syncthreads();
  if (L == 0) {
    int i1 = 0; float v1 = ps[0];
#pragma unroll
    for (int e = 1; e < 8; ++e) if (ps[e] > v1) { v1 = ps[e]; i1 = e; }
    float v2 = -1.f; int i2 = 0;
#pragma unroll
    for (int e = 0; e < 8; ++e) if (e != i1 && ps[e] > v2) { v2 = ps[e]; i2 = e; }
    float s = v1 + v2;
    float w[8];
#pragma unroll
    for (int e = 0; e < 8; ++e) w[e] = 0.f;
    w[i1] = v1 / s; w[i2] = v2 / s;
#pragma unroll
    for (int e = 0; e < 8; ++e) wfull[(size_t)n * 8 + e] = w[e];
  }
}

// ---------------- weighted expert combine -> pk bf16 (K=64 for c2s) ----------------
__global__ void combine_kernel(const float* __restrict__ eo, const float* __restrict__ wfull,
                               ushort* __restrict__ exopk, int M) {
  int t = blockIdx.x * 256 + threadIdx.x;
  int n = t >> 6, m = t & 63;
  float acc = 0.f;
#pragma unroll
  for (int e = 0; e < 8; ++e)
    acc = fmaf(wfull[(size_t)n * 8 + e], eo[((size_t)e * M + n) * 64 + m], acc);
  exopk[((size_t)(m >> 3) * M + n) * 8 + (m & 7)] = f2bf(acc);
}

extern "C" void kernel_launch(void* const* d_in, const int* in_sizes, int n_in,
                              void* d_out, int out_size, void* d_ws, size_t ws_size,
                              hipStream_t stream) {
  const int*   ids   = (const int*)  d_in[0];
  const float* emb   = (const float*)d_in[1];
  const float* enc_W = (const float*)d_in[2];
  const float* enc_b = (const float*)d_in[3];
  const float* s2c_W = (const float*)d_in[4];
  const float* s2c_b = (const float*)d_in[5];
  const float* rW1   = (const float*)d_in[6];
  const float* rb1   = (const float*)d_in[7];
  const float* rW2   = (const float*)d_in[8];
  const float* rb2   = (const float*)d_in[9];
  const float* eW1   = (const float*)d_in[10];
  const float* eb1   = (const float*)d_in[11];
  const float* eW2   = (const float*)d_in[12];
  const float* eb2   = (const float*)d_in[13];
  const float* c2s_W = (const float*)d_in[14];
  const float* c2s_b = (const float*)d_in[15];
  const float* dec_W = (const float*)d_in[16];
  const float* dec_b = (const float*)d_in[17];
  const float* out_W = (const float*)d_in[18];
  const float* out_b = (const float*)d_in[19];
  (void)in_sizes; (void)n_in; (void)out_size; (void)ws_size;

  const int M = 4096, D = 1024, H = 1024, Mm = 64, E = 8, V = 32000, HE = 512;

  char* p = (char*)d_ws;
  auto alloc = [&](size_t bytes) { void* r = (void*)p; p += (bytes + 255) & ~(size_t)255; return r; };
  ushort* xpk    = (ushort*)alloc((size_t)M * D * 2);
  ushort* encWpk = (ushort*)alloc((size_t)D * H * 2);
  float*  spikes = (float*) alloc((size_t)M * H * 4);
  float*  cont   = (float*) alloc((size_t)M * Mm * 4);
  ushort* contpk = (ushort*)alloc((size_t)M * Mm * 2);
  float*  wfull  = (float*) alloc((size_t)M * E * 4);
  ushort* eW1pk  = (ushort*)alloc((size_t)E * Mm * HE * 2);
  ushort* eW2pk  = (ushort*)alloc((size_t)E * HE * Mm * 2);
  ushort* h1pk   = (ushort*)alloc((size_t)E * M * HE * 2);
  float*  eo     = (float*) alloc((size_t)E * M * Mm * 4);
  ushort* exopk  = (ushort*)alloc((size_t)M * Mm * 2);
  ushort* c2sWpk = (ushort*)alloc((size_t)Mm * H * 2);
  ushort* smoepk = (ushort*)alloc((size_t)M * H * 2);
  ushort* decWpk = (ushort*)alloc((size_t)H * D * 2);
  ushort* decpk  = (ushort*)alloc((size_t)M * D * 2);
  ushort* outWpk = (ushort*)alloc((size_t)D * V * 2);

  float* logits = (float*)d_out;
  float* probs  = logits + (size_t)M * V;

  // weight packs (fp32 -> bf16 k-packed)
  pack_w_kernel<<<dim3(((D / 8) * H + 255) / 256, 1), 256, 0, stream>>>(enc_W, encWpk, D, H);
  pack_w_kernel<<<dim3(((Mm / 8) * HE + 255) / 256, E), 256, 0, stream>>>(eW1, eW1pk, Mm, HE);
  pack_w_kernel<<<dim3(((HE / 8) * Mm + 255) / 256, E), 256, 0, stream>>>(eW2, eW2pk, HE, Mm);
  pack_w_kernel<<<dim3(((Mm / 8) * H + 255) / 256, 1), 256, 0, stream>>>(c2s_W, c2sWpk, Mm, H);
  pack_w_kernel<<<dim3(((H / 8) * D + 255) / 256, 1), 256, 0, stream>>>(dec_W, decWpk, H, D);
  pack_w_kernel<<<dim3(((D / 8) * V + 255) / 256, 1), 256, 0, stream>>>(out_W, outWpk, D, V);

  // 1) embed gather -> pk
  embed_pk_kernel<<<dim3(M / 256, D / 8), 256, 0, stream>>>(ids, emb, xpk, M);
  // 2) enc: sigmoid(x @ enc_W + b) -> fp32 (router path needs precision)
  gemm_pk<2, 2, 4, 4, 1, 0><<<dim3(M / 128, H / 128, 1), 256, 0, stream>>>(
      xpk, encWpk, enc_b, spikes, M, H, D, 0, 0, 0, 0);
  // 3) s2c fp32
  s2c_kernel<<<dim3(M / 4), 256, 0, stream>>>(spikes, s2c_W, s2c_b, cont, contpk, M);
  // 4) router fp32
  router_kernel<<<dim3(M), 64, 0, stream>>>(cont, rW1, rb1, rW2, rb2, probs, wfull);
  // 5) experts: h1 = relu(cont @ eW1 + eb1)  [batched over E]
  gemm_pk<2, 2, 4, 4, 2, 1><<<dim3(M / 128, HE / 128, E), 256, 0, stream>>>(
      contpk, eW1pk, eb1, h1pk, M, HE, Mm, 0, (long)Mm * HE, HE, (long)M * HE);
  //    eo = h1 @ eW2 + eb2   (N=64 tile variant)
  gemm_pk<4, 1, 2, 4, 0, 0><<<dim3(M / 128, 1, E), 256, 0, stream>>>(
      h1pk, eW2pk, eb2, eo, M, Mm, HE, (long)M * HE, (long)HE * Mm, Mm, (long)M * Mm);
  // 6) weighted combine (top-2 weights, zeros elsewhere)
  combine_kernel<<<dim3(M * Mm / 256), 256, 0, stream>>>(eo, wfull, exopk, M);
  // 7) c2s: sigmoid(expert_out @ c2s_W + b) -> pk
  gemm_pk<2, 2, 4, 4, 1, 1><<<dim3(M / 128, H / 128, 1), 256, 0, stream>>>(
      exopk, c2sWpk, c2s_b, smoepk, M, H, Mm, 0, 0, 0, 0);
  // 8) dec: sigmoid(spikes @ dec_W + b) -> pk
  gemm_pk<2, 2, 4, 4, 1, 1><<<dim3(M / 128, D / 128, 1), 256, 0, stream>>>(
      smoepk, decWpk, dec_b, decpk, M, D, H, 0, 0, 0, 0);
  // 9) out: logits = decoded @ out_W + b  (fp32 out, the 268 GFLOP GEMM)
  gemm_pk<2, 2, 4, 4, 0, 0><<<dim3(M / 128, V / 128, 1), 256, 0, stream>>>(
      decpk, outWpk, out_b, logits, M, V, D, 0, 0, 0, 0);
}